// Round 3
// baseline (116.472 us; speedup 1.0000x reference)
//
#include <hip/hip_runtime.h>

// LearnedTaskSpecificLinear: out[n,o] = sum_i x[n,i] * W[task_ids[n], i, o]
// x: [2048,512] f32, task_ids: [2048] i32, W: [64,512,512] f32, out: [2048,512] f32
//
// Round 3: 3-kernel pipeline for concurrency.
//   K1: per-task rowlists via atomics (order-independent results).
//   K2: grid (8 colchunk, 64 task, 4 kslice) = 2048 blocks x 256 thr.
//       Wave w owns K-tile [ks*128 + w*32, +32): wave-private LDS tiles,
//       f16 MFMA 16x16x32, cross-wave reduce -> f32 partial per kslice.
//       W read exactly once from HBM (K-partition is disjoint).
//   K3: sum 4 partial slices -> out.

#define KDIM  512
#define NDIM  512
#define TSTR  40   // f16 elems per tile row (80 B): 16B-aligned b128 rows

typedef _Float16 f16x8 __attribute__((ext_vector_type(8)));
typedef _Float16 f16x4 __attribute__((ext_vector_type(4)));
typedef float    f32x4 __attribute__((ext_vector_type(4)));

__global__ __launch_bounds__(256) void k_rowlist(
    const int* __restrict__ tids, int* __restrict__ cnt,
    int* __restrict__ rows, int n_rows)
{
    const int i = blockIdx.x * 256 + threadIdx.x;
    if (i < n_rows) {
        const int t = tids[i];
        const int p = atomicAdd(&cnt[t], 1);
        rows[t * 2048 + p] = i;
    }
}

__global__ __launch_bounds__(256) void k_gemm(
    const float* __restrict__ x, const float* __restrict__ W,
    const int* __restrict__ cnt, const int* __restrict__ rows,
    float* __restrict__ part)
{
    const int tid  = threadIdx.x;
    const int lane = tid & 63;
    const int wv   = tid >> 6;
    const int c0   = blockIdx.x * 64;
    const int task = blockIdx.y;
    const int ks   = blockIdx.z;

    const int count = cnt[task];
    if (count == 0) return;

    const int k0 = ks * 128 + wv * 32;   // this wave's 32-deep K tile

    __shared__ __align__(16) char smem[40960];
    _Float16* Wt  = (_Float16*)(smem + wv * 10240);          // [64 c][TSTR]
    _Float16* xs  = (_Float16*)(smem + wv * 10240 + 5120);   // [64 r][TSTR]
    float*    red = (float*)smem;                            // [4][2048] alias

    const int ml = lane & 15;
    const int q  = lane >> 4;
    const float* Wg = W + (size_t)task * KDIM * NDIM + c0;
    const int*   rl = rows + task * 2048;
    float*       pb = part + (size_t)ks * 2048 * NDIM;

    for (int g0 = 0; g0 < count; g0 += 64) {
        // ---- issue all gather indices + global loads up front ----
        int rowv[8];
        #pragma unroll
        for (int u = 0; u < 8; ++u) {
            const int rr = g0 + u * 8 + (lane >> 3);
            rowv[u] = rl[(rr < count) ? rr : g0];
        }
        float4 xv[8];
        #pragma unroll
        for (int u = 0; u < 8; ++u)
            xv[u] = *(const float4*)(x + (size_t)rowv[u] * KDIM + k0 + (lane & 7) * 4);

        const int ko = q * 8;            // this lane's k-octet within the tile
        float4 wr[8];
        #pragma unroll
        for (int j = 0; j < 8; ++j)
            wr[j] = *(const float4*)(Wg + (size_t)(k0 + ko + j) * NDIM + ml * 4);

        // ---- x tile: [r][k] f16, natural k-minor (conflict-free b64) ----
        #pragma unroll
        for (int u = 0; u < 8; ++u) {
            const int r = u * 8 + (lane >> 3);
            f16x4 h = {(_Float16)xv[u].x, (_Float16)xv[u].y,
                       (_Float16)xv[u].z, (_Float16)xv[u].w};
            *(f16x4*)(xs + r * TSTR + (lane & 7) * 4) = h;
        }
        // ---- W tile transposed: col c = ml*4+j gets k-octet ko (b128, bank-floor) ----
        {
            f16x8 h0 = {(_Float16)wr[0].x, (_Float16)wr[1].x, (_Float16)wr[2].x, (_Float16)wr[3].x,
                        (_Float16)wr[4].x, (_Float16)wr[5].x, (_Float16)wr[6].x, (_Float16)wr[7].x};
            f16x8 h1 = {(_Float16)wr[0].y, (_Float16)wr[1].y, (_Float16)wr[2].y, (_Float16)wr[3].y,
                        (_Float16)wr[4].y, (_Float16)wr[5].y, (_Float16)wr[6].y, (_Float16)wr[7].y};
            f16x8 h2 = {(_Float16)wr[0].z, (_Float16)wr[1].z, (_Float16)wr[2].z, (_Float16)wr[3].z,
                        (_Float16)wr[4].z, (_Float16)wr[5].z, (_Float16)wr[6].z, (_Float16)wr[7].z};
            f16x8 h3 = {(_Float16)wr[0].w, (_Float16)wr[1].w, (_Float16)wr[2].w, (_Float16)wr[3].w,
                        (_Float16)wr[4].w, (_Float16)wr[5].w, (_Float16)wr[6].w, (_Float16)wr[7].w};
            _Float16* wp = Wt + (ml * 4) * TSTR + ko;
            *(f16x8*)(wp)            = h0;
            *(f16x8*)(wp + TSTR)     = h1;
            *(f16x8*)(wp + 2 * TSTR) = h2;
            *(f16x8*)(wp + 3 * TSTR) = h3;
        }

        // ---- fragments + 16 mfma (wave-private: no barrier, lgkmcnt only) ----
        f16x8 af[4], bf[4];
        #pragma unroll
        for (int rt = 0; rt < 4; ++rt)
            af[rt] = *(const f16x8*)(xs + (rt * 16 + ml) * TSTR + q * 8);
        #pragma unroll
        for (int ct = 0; ct < 4; ++ct)
            bf[ct] = *(const f16x8*)(Wt + (ct * 16 + ml) * TSTR + q * 8);

        f32x4 acc[4][4] = {};
        #pragma unroll
        for (int rt = 0; rt < 4; ++rt)
            #pragma unroll
            for (int ct = 0; ct < 4; ++ct)
                acc[rt][ct] = __builtin_amdgcn_mfma_f32_16x16x32_f16(
                    af[rt], bf[ct], acc[rt][ct], 0, 0, 0);

        // ---- cross-wave K-reduction (4 waves -> one 128-deep partial) ----
        #pragma unroll
        for (int h = 0; h < 2; ++h) {
            __syncthreads();
            #pragma unroll
            for (int rt2 = 0; rt2 < 2; ++rt2) {
                const int rt = h * 2 + rt2;
                #pragma unroll
                for (int ct = 0; ct < 4; ++ct)
                    #pragma unroll
                    for (int rg = 0; rg < 4; ++rg)
                        red[wv * 2048 + (rt2 * 16 + q * 4 + rg) * 64 + ct * 16 + ml]
                            = acc[rt][ct][rg];
            }
            __syncthreads();
            #pragma unroll
            for (int t2 = 0; t2 < 2; ++t2) {
                const int idx = t2 * 1024 + tid * 4;
                const float4 a0 = *(const float4*)&red[idx];
                const float4 a1 = *(const float4*)&red[2048 + idx];
                const float4 a2 = *(const float4*)&red[4096 + idx];
                const float4 a3 = *(const float4*)&red[6144 + idx];
                float4 s;
                s.x = a0.x + a1.x + a2.x + a3.x;
                s.y = a0.y + a1.y + a2.y + a3.y;
                s.z = a0.z + a1.z + a2.z + a3.z;
                s.w = a0.w + a1.w + a2.w + a3.w;
                const int r  = h * 32 + (idx >> 6);
                const int c  = idx & 63;
                const int rr = g0 + r;
                if (rr < count)
                    *(float4*)(pb + (size_t)rl[rr] * NDIM + c0 + c) = s;
            }
        }
        __syncthreads();   // red region becomes tiles again next pass
    }
}

__global__ __launch_bounds__(256) void k_reduce(
    const float* __restrict__ part, float* __restrict__ out)
{
    const int i = blockIdx.x * 256 + threadIdx.x;       // float4 index
    const f32x4* p = (const f32x4*)part;
    const f32x4 a = p[i];
    const f32x4 b = p[262144 + i];
    const f32x4 c = p[524288 + i];
    const f32x4 d = p[786432 + i];
    f32x4 s = a + b + c + d;
    ((f32x4*)out)[i] = s;
}

extern "C" void kernel_launch(void* const* d_in, const int* in_sizes, int n_in,
                              void* d_out, int out_size, void* d_ws, size_t ws_size,
                              hipStream_t stream) {
    const float* x    = (const float*)d_in[0];
    const int*   tids = (const int*)d_in[1];
    const float* W    = (const float*)d_in[2];
    float*       out  = (float*)d_out;
    const int n_rows  = in_sizes[1];   // 2048

    int*   cnt  = (int*)d_ws;                          // 64 counters
    int*   rows = (int*)d_ws + 64;                     // 64 x 2048
    float* part = (float*)((char*)d_ws + (1 << 20));   // 4 x 2048 x 512 f32 = 16 MB

    hipMemsetAsync(cnt, 0, 64 * sizeof(int), stream);
    k_rowlist<<<dim3((n_rows + 255) / 256), dim3(256), 0, stream>>>(tids, cnt, rows, n_rows);
    k_gemm<<<dim3(8, 64, 4), dim3(256), 0, stream>>>(x, W, cnt, rows, part);
    k_reduce<<<dim3(2048 * 512 / 4 / 256), dim3(256), 0, stream>>>(part, out);
}

// Round 4
// 112.632 us; speedup vs baseline: 1.0341x; 1.0341x over previous
//
#include <hip/hip_runtime.h>

// LearnedTaskSpecificLinear: out[n,o] = sum_i x[n,i] * W[task_ids[n], i, o]
// x: [2048,512] f32, task_ids: [2048] i32, W: [64,512,512] f32, out: [2048,512] f32
//
// Round 4: 2 launches, no K-reduction.
//   K1: rowlist via LDS atomics, single block (zeroes its own counters).
//   K2: grid (16 col-chunks of 32, 64 tasks) = 1024 blocks x 256 thr (4 waves).
//       Wave w owns rows [w*16, w*16+16) over FULL K=512 -> no cross-wave
//       reduce, direct store. A-frags: in-register f32->f16 from gathered x
//       (A row index == lane&15 == wave-local row; x never touches LDS).
//       W: two 256-deep chunks staged to LDS f16, k-octet XOR-swizzled
//       (phys_oct = oct ^ (col&7)) -> conflict-free b128 writes AND reads.
//       W read from HBM exactly once across the grid (disjoint cols).

#define NDIM 512
#define KDIM 512
#define NCOL 32
#define KCH  256

typedef _Float16 f16x8 __attribute__((ext_vector_type(8)));
typedef float    f32x4 __attribute__((ext_vector_type(4)));

__global__ __launch_bounds__(256) void k_rowlist(
    const int* __restrict__ tids, int* __restrict__ cnt,
    int* __restrict__ rows, int n_rows)
{
    __shared__ int lc[64];
    const int tid = threadIdx.x;
    if (tid < 64) lc[tid] = 0;
    __syncthreads();
    for (int i = tid; i < n_rows; i += 256) {
        const int t = tids[i];
        const int p = atomicAdd(&lc[t], 1);
        rows[t * 2048 + p] = i;
    }
    __syncthreads();
    if (tid < 64) cnt[tid] = lc[tid];
}

__global__ __launch_bounds__(256) void k_gemm(
    const float* __restrict__ x, const float* __restrict__ W,
    const int* __restrict__ cnt, const int* __restrict__ rows,
    float* __restrict__ out)
{
    const int tid  = threadIdx.x;
    const int lane = tid & 63;
    const int wv   = tid >> 6;
    const int c0   = blockIdx.x * NCOL;
    const int task = blockIdx.y;

    const int count = cnt[task];
    if (count == 0) return;

    __shared__ __align__(16) _Float16 Wt[NCOL * KCH];   // 16 KB, [c][k] xor-swizzled

    const int ml = lane & 15;
    const int q  = lane >> 4;
    const float* Wg = W + (size_t)task * KDIM * NDIM + c0;
    const int*   rl = rows + task * 2048;

    // staging coords: this thread stages cols sc4..sc4+3 x k-octet soct
    const int sc4  = (tid & 7) * 4;
    const int soct = tid >> 3;          // 0..31

    for (int g0 = 0; g0 < count; g0 += 64) {
        const int rr = g0 + wv * 16 + ml;
        const int rowid = rl[(rr < count) ? rr : 0];
        const float* xrow = x + (size_t)rowid * KDIM;

        f32x4 acc[2] = {};

        #pragma unroll
        for (int kc = 0; kc < 2; ++kc) {
            const int kb = kc * KCH;

            // ---- stage W chunk [256 k][32 c]: 8 float4 loads, 4 b128 swizzled writes
            float4 wr[8];
            #pragma unroll
            for (int j = 0; j < 8; ++j)
                wr[j] = *(const float4*)(Wg + (size_t)(kb + soct * 8 + j) * NDIM + sc4);
            #pragma unroll
            for (int j2 = 0; j2 < 4; ++j2) {
                f16x8 h;
                #pragma unroll
                for (int j = 0; j < 8; ++j)
                    h[j] = (_Float16)(((const float*)&wr[j])[j2]);
                const int c  = sc4 + j2;
                const int po = soct ^ (c & 7);
                *(f16x8*)(&Wt[c * KCH + po * 8]) = h;
            }

            // ---- prefetch this wave's x for the chunk (independent of LDS)
            float4 xa[16];
            #pragma unroll
            for (int ks = 0; ks < 8; ++ks) {
                xa[2 * ks]     = *(const float4*)(xrow + kb + ks * 32 + q * 8);
                xa[2 * ks + 1] = *(const float4*)(xrow + kb + ks * 32 + q * 8 + 4);
            }

            __syncthreads();

            // ---- compute: 8 k-subtiles x 2 col-tiles
            #pragma unroll
            for (int ks = 0; ks < 8; ++ks) {
                const float4 a0 = xa[2 * ks];
                const float4 a1 = xa[2 * ks + 1];
                f16x8 af;
                af[0] = (_Float16)a0.x; af[1] = (_Float16)a0.y;
                af[2] = (_Float16)a0.z; af[3] = (_Float16)a0.w;
                af[4] = (_Float16)a1.x; af[5] = (_Float16)a1.y;
                af[6] = (_Float16)a1.z; af[7] = (_Float16)a1.w;
                #pragma unroll
                for (int ct = 0; ct < 2; ++ct) {
                    const int cB = ct * 16 + ml;
                    const int po = (ks * 4 + q) ^ (cB & 7);
                    const f16x8 bf = *(const f16x8*)(&Wt[cB * KCH + po * 8]);
                    acc[ct] = __builtin_amdgcn_mfma_f32_16x16x32_f16(af, bf, acc[ct], 0, 0, 0);
                }
            }
            __syncthreads();
        }

        // ---- store: C/D row = q*4+rg (wave-local), col = ct*16+ml
        #pragma unroll
        for (int rg = 0; rg < 4; ++rg) {
            const int rr2 = g0 + wv * 16 + q * 4 + rg;
            if (rr2 < count) {
                float* op = out + (size_t)rl[rr2] * NDIM + c0 + ml;
                op[0]  = acc[0][rg];
                op[16] = acc[1][rg];
            }
        }
    }
}

extern "C" void kernel_launch(void* const* d_in, const int* in_sizes, int n_in,
                              void* d_out, int out_size, void* d_ws, size_t ws_size,
                              hipStream_t stream) {
    const float* x    = (const float*)d_in[0];
    const int*   tids = (const int*)d_in[1];
    const float* W    = (const float*)d_in[2];
    float*       out  = (float*)d_out;
    const int n_rows  = in_sizes[1];   // 2048

    int* cnt  = (int*)d_ws;        // 64
    int* rows = (int*)d_ws + 64;   // 64 x 2048

    k_rowlist<<<dim3(1), dim3(256), 0, stream>>>(tids, cnt, rows, n_rows);
    k_gemm<<<dim3(NDIM / NCOL, 64), dim3(256), 0, stream>>>(x, W, cnt, rows, out);
}

// Round 5
// 108.023 us; speedup vs baseline: 1.0782x; 1.0427x over previous
//
#include <hip/hip_runtime.h>

// LearnedTaskSpecificLinear: out[n,o] = sum_i x[n,i] * W[task_ids[n], i, o]
// x: [2048,512] f32, task_ids: [2048] i32, W: [64,512,512] f32, out: [2048,512] f32
//
// Round 5: single fused launch.
//   grid (16 col-chunks of 32, 64 tasks) x 256 thr (4 waves), ~34 KB LDS -> 4 blocks/CU.
//   Per block: wave w ballot-scans tids quarter [w*512,(w+1)*512) -> wave-local
//   rowlist (deterministic, no atomics). W (32 cols x 512 k) staged to LDS f16
//   ONCE (outside row loop), k-octet XOR-swizzled (po = oct ^ (c&7)): b128
//   writes and B-frag reads both at conflict-free baseline. Issue order: tids
//   loads -> W loads -> ballot scan (hides W HBM latency) -> cvt+LDS -> barrier
//   -> compact -> per-wave rows [w*16,w*16+16) over full K, A-frags straight
//   from global x with in-register f32->f16 (x never touches LDS), no
//   cross-wave reduce, direct store. W read from HBM exactly once grid-wide.

#define NDIM 512
#define KDIM 512
#define NCOL 32

typedef _Float16 f16x8 __attribute__((ext_vector_type(8)));
typedef float    f32x4 __attribute__((ext_vector_type(4)));

__global__ __launch_bounds__(256) void k_fused(
    const float* __restrict__ x,
    const int*   __restrict__ tids,
    const float* __restrict__ W,
    float*       __restrict__ out,
    int n_rows)
{
    const int tid  = threadIdx.x;
    const int lane = tid & 63;
    const int wv   = tid >> 6;
    const int c0   = blockIdx.x * NCOL;
    const int task = blockIdx.y;

    __shared__ __align__(16) _Float16 Wt[NCOL * KDIM];   // 32 KB, [c][k] swizzled
    __shared__ unsigned short rlw[4 * 128];              // per-wave lists
    __shared__ unsigned short rl[256];                   // compacted list
    __shared__ int wcnt[4];

    // ---- issue tids loads first (8 per lane, this wave's quarter)
    int trow[8], tval[8];
    #pragma unroll
    for (int it = 0; it < 8; ++it) {
        trow[it] = wv * 512 + it * 64 + lane;
        tval[it] = (trow[it] < n_rows) ? tids[trow[it]] : -1;
    }

    // ---- issue all W loads (independent; latency hidden behind the scan)
    const int sc4   = (tid & 7) * 4;      // 4-col group
    const int obase = tid >> 3;           // k-octet 0..31 (+32 for 2nd half)
    const float* Wg = W + (size_t)task * KDIM * NDIM + c0;
    float4 wr[16];
    #pragma unroll
    for (int j = 0; j < 8; ++j)
        wr[j] = *(const float4*)(Wg + (size_t)(obase * 8 + j) * NDIM + sc4);
    #pragma unroll
    for (int j = 0; j < 8; ++j)
        wr[8 + j] = *(const float4*)(Wg + (size_t)((obase + 32) * 8 + j) * NDIM + sc4);

    // ---- ballot scan of this wave's quarter (waits only the tids loads)
    int cloc = 0;
    #pragma unroll
    for (int it = 0; it < 8; ++it) {
        const bool m = (tval[it] == task);
        const unsigned long long bal = __ballot(m);
        const int rank = __popcll(bal & ((1ull << lane) - 1ull));
        if (m) rlw[wv * 128 + cloc + rank] = (unsigned short)trow[it];
        cloc += __popcll(bal);
    }
    if (lane == 0) wcnt[wv] = cloc;

    // ---- W f32->f16 + swizzled LDS write (4 b128 per half per thread)
    #pragma unroll
    for (int h = 0; h < 2; ++h) {
        const int oct = obase + h * 32;
        #pragma unroll
        for (int j2 = 0; j2 < 4; ++j2) {
            f16x8 h8;
            #pragma unroll
            for (int j = 0; j < 8; ++j)
                h8[j] = (_Float16)(((const float*)&wr[h * 8 + j])[j2]);
            const int c  = sc4 + j2;
            const int po = oct ^ (c & 7);
            *(f16x8*)&Wt[c * KDIM + po * 8] = h8;
        }
    }

    __syncthreads();

    // ---- compact the 4 wave-lists into rl[]
    const int n0 = wcnt[0], n1 = wcnt[1], n2 = wcnt[2], n3 = wcnt[3];
    const int o1 = n0, o2 = n0 + n1, o3 = o2 + n2;
    const int count = o3 + n3;
    if (tid < count && tid < 256) {
        int w, base;
        if (tid < o1)      { w = 0; base = 0;  }
        else if (tid < o2) { w = 1; base = o1; }
        else if (tid < o3) { w = 2; base = o2; }
        else               { w = 3; base = o3; }
        rl[tid] = rlw[w * 128 + tid - base];
    }
    __syncthreads();

    if (count == 0) return;

    const int ml = lane & 15;
    const int q  = lane >> 4;

    for (int g0 = 0; g0 < count; g0 += 64) {
        const int rr = g0 + wv * 16 + ml;
        const int rowid = rl[(rr < count) ? rr : 0];
        const float* xrow = x + (size_t)rowid * KDIM;

        f32x4 acc[2] = {};
        #pragma unroll
        for (int p = 0; p < 2; ++p) {
            const int kb = p * 256;
            float4 xa[16];
            #pragma unroll
            for (int ks = 0; ks < 8; ++ks) {
                xa[2 * ks]     = *(const float4*)(xrow + kb + ks * 32 + q * 8);
                xa[2 * ks + 1] = *(const float4*)(xrow + kb + ks * 32 + q * 8 + 4);
            }
            #pragma unroll
            for (int ks = 0; ks < 8; ++ks) {
                f16x8 af;
                const float* a0 = (const float*)&xa[2 * ks];
                #pragma unroll
                for (int j = 0; j < 8; ++j) af[j] = (_Float16)a0[j];
                #pragma unroll
                for (int ct = 0; ct < 2; ++ct) {
                    const int cB = ct * 16 + ml;
                    const int po = (p * 32 + ks * 4 + q) ^ (cB & 7);
                    const f16x8 bf = *(const f16x8*)&Wt[cB * KDIM + po * 8];
                    acc[ct] = __builtin_amdgcn_mfma_f32_16x16x32_f16(af, bf, acc[ct], 0, 0, 0);
                }
            }
        }

        // ---- store: C/D row = q*4+rg (wave-local), col = ct*16+ml
        #pragma unroll
        for (int rg = 0; rg < 4; ++rg) {
            const int rr2 = g0 + wv * 16 + q * 4 + rg;
            if (rr2 < count) {
                float* op = out + (size_t)rl[rr2] * NDIM + c0 + ml;
                op[0]  = acc[0][rg];
                op[16] = acc[1][rg];
            }
        }
    }
}

extern "C" void kernel_launch(void* const* d_in, const int* in_sizes, int n_in,
                              void* d_out, int out_size, void* d_ws, size_t ws_size,
                              hipStream_t stream) {
    const float* x    = (const float*)d_in[0];
    const int*   tids = (const int*)d_in[1];
    const float* W    = (const float*)d_in[2];
    float*       out  = (float*)d_out;
    const int n_rows  = in_sizes[1];   // 2048

    k_fused<<<dim3(NDIM / NCOL, 64), dim3(256), 0, stream>>>(x, tids, W, out, n_rows);
}